// Round 14
// baseline (36.761 us; speedup 1.0000x reference)
//
#include <hip/hip_runtime.h>
#include <hip/hip_bf16.h>

#define FFN 2048
#define LN_EPS 1e-5f

typedef __attribute__((ext_vector_type(8))) short bf16x8;
typedef __attribute__((ext_vector_type(4))) float f32x4;

union FragU { bf16x8 v; unsigned u[4]; uint4 q; };

static __device__ __forceinline__ unsigned cvtpk(float lo, float hi) {
    unsigned r;
    asm("v_cvt_pk_bf16_f32 %0, %1, %2" : "=v"(r) : "v"(lo), "v"(hi));
    return r;
}

static __device__ __forceinline__ ushort to_bf16(float f) {   // RNE, finite inputs
    unsigned u = __float_as_uint(f);
    u += 0x7fffu + ((u >> 16) & 1u);
    return (ushort)(u >> 16);
}

// ---------------- prep: packed per-lane 16x16x32 fragments (R3-R13-verified values) --------
// record = 33 uint4: slot0 = zeros (inactive-lane broadcast), slots 1..32 = real lanes.
//  pW1: rec = cc*2+s at rec*33      (l32: c=l32&15, g=l32>>4; f=cc*32+s*16+c;
//                                    g0: W1[f][j], g1: j==0 ? b1[f] : 0)
//  pW2: rec = cc at 4224+cc*33      (l32: g=l32>>3, c=l32&7;
//                                    v[j] = W2[c*FFN + cc*32 + 4g + (j&3) + 16*(j>>2)])
__global__ __launch_bounds__(256) void tbq_prep(
    const float* __restrict__ W1, const float* __restrict__ b1,
    const float* __restrict__ W2, uint4* __restrict__ ws)
{
    const int idx = blockIdx.x * 256 + threadIdx.x;
    if (idx >= 6336) return;
    ushort v[8] = {0,0,0,0,0,0,0,0};
    if (idx < 4224) {
        const int rec = idx / 33, r = idx % 33;
        if (r) {
            const int l32 = r - 1, c = l32 & 15, g = l32 >> 4;
            const int s = rec & 1, cc = rec >> 1;
            const int f = cc * 32 + s * 16 + c;
            if (g == 0) {
                #pragma unroll
                for (int j = 0; j < 8; ++j) v[j] = to_bf16(W1[f * 8 + j]);
            } else {
                v[0] = to_bf16(b1[f]);
            }
        }
    } else {
        const int i2 = idx - 4224;
        const int rec = i2 / 33, r = i2 % 33;
        if (r) {
            const int l32 = r - 1, g = l32 >> 3, c = l32 & 7, cc = rec;
            #pragma unroll
            for (int j = 0; j < 8; ++j) {
                const int fl = 4 * g + (j & 3) + 16 * (j >> 2);
                v[j] = to_bf16(W2[c * FFN + cc * 32 + fl]);
            }
        }
    }
    union { ushort s[8]; uint4 q; } pk;
    #pragma unroll
    for (int j = 0; j < 8; ++j) pk.s[j] = v[j];
    ws[idx] = pk.q;
}

// One T-body: 2 zero-C MFMA -> pack(relu+bf16) -> acc MFMA, all in fixed scratch regs.
// s_nop padding: MFMA(4-pass)->VALU read ~<=16 cyc (2x s_nop 7); VALU->MFMA read ~<=4 (s_nop 3).
#define TBODY_BANK(ACC, F0V, F1V, A2V, B1V, CA, CB, W0, W1R, W2R, W3)                 \
    asm volatile(                                                                     \
        "v_mfma_f32_16x16x32_bf16 " CA ", %[f0], %[b1], %[z]\n\t"                     \
        "v_mfma_f32_16x16x32_bf16 " CB ", %[f1], %[b1], %[z]\n\t"                     \
        "s_nop 7\n\t"                                                                 \
        "s_nop 7\n\t"                                                                 \
        "v_cvt_pk_bf16_f32 " W0 ", " CA "[0]\n\t"                                     \
        : : : );  /* placeholder - real macro below */

// (real implementation uses explicit register names; see TB_A / TB_B)

#define TB_A(ACC, F0V, F1V, A2V, B1V)                                                  \
    asm volatile(                                                                      \
        "v_mfma_f32_16x16x32_bf16 v[40:43], %[f0], %[b1], %[z]\n\t"                    \
        "v_mfma_f32_16x16x32_bf16 v[44:47], %[f1], %[b1], %[z]\n\t"                    \
        "s_nop 7\n\t"                                                                  \
        "s_nop 7\n\t"                                                                  \
        "v_cvt_pk_bf16_f32 v48, v40, v41\n\t"                                          \
        "v_cvt_pk_bf16_f32 v49, v42, v43\n\t"                                          \
        "v_cvt_pk_bf16_f32 v50, v44, v45\n\t"                                          \
        "v_cvt_pk_bf16_f32 v51, v46, v47\n\t"                                          \
        "v_pk_max_f16 v48, v48, 0\n\t"                                                 \
        "v_pk_max_f16 v49, v49, 0\n\t"                                                 \
        "v_pk_max_f16 v50, v50, 0\n\t"                                                 \
        "v_pk_max_f16 v51, v51, 0\n\t"                                                 \
        "s_nop 3\n\t"                                                                  \
        "v_mfma_f32_16x16x32_bf16 %[acc], %[a2], v[48:51], %[acc]"                     \
        : [acc] "+v"(ACC)                                                              \
        : [f0] "v"(F0V), [f1] "v"(F1V), [a2] "v"(A2V), [b1] "v"(B1V), [z] "v"(z4)      \
        : "v40","v41","v42","v43","v44","v45","v46","v47","v48","v49","v50","v51")

#define TB_B(ACC, F0V, F1V, A2V, B1V)                                                  \
    asm volatile(                                                                      \
        "v_mfma_f32_16x16x32_bf16 v[52:55], %[f0], %[b1], %[z]\n\t"                    \
        "v_mfma_f32_16x16x32_bf16 v[56:59], %[f1], %[b1], %[z]\n\t"                    \
        "s_nop 7\n\t"                                                                  \
        "s_nop 7\n\t"                                                                  \
        "v_cvt_pk_bf16_f32 v60, v52, v53\n\t"                                          \
        "v_cvt_pk_bf16_f32 v61, v54, v55\n\t"                                          \
        "v_cvt_pk_bf16_f32 v62, v56, v57\n\t"                                          \
        "v_cvt_pk_bf16_f32 v63, v58, v59\n\t"                                          \
        "v_pk_max_f16 v60, v60, 0\n\t"                                                 \
        "v_pk_max_f16 v61, v61, 0\n\t"                                                 \
        "v_pk_max_f16 v62, v62, 0\n\t"                                                 \
        "v_pk_max_f16 v63, v63, 0\n\t"                                                 \
        "s_nop 3\n\t"                                                                  \
        "v_mfma_f32_16x16x32_bf16 %[acc], %[a2], v[60:63], %[acc]"                     \
        : [acc] "+v"(ACC)                                                              \
        : [f0] "v"(F0V), [f1] "v"(F1V), [a2] "v"(A2V), [b1] "v"(B1V), [z] "v"(z4)      \
        : "v52","v53","v54","v55","v56","v57","v58","v59","v60","v61","v62","v63")

// ---------------- main: 128 tokens/block, 4 waves f-split, asm T-body ----------------
__global__ __launch_bounds__(256) void tbq_mfma(
    const float* __restrict__ x,
    const float* __restrict__ Wq,
    const float* __restrict__ Wo,
    const float* __restrict__ b2,
    const float* __restrict__ g1,
    const float* __restrict__ beta1,
    const float* __restrict__ g2,
    const float* __restrict__ beta2,
    const uint4* __restrict__ ws,
    float* __restrict__ out)
{
    __shared__ __align__(16) uint4 mS[128];           // 2KB  m (bf16) per token
    __shared__ __align__(16) float part[4][128][8];   // 16KB per-wave partial ffn

    const int tid  = threadIdx.x;
    const int lane = tid & 63;
    const int wv   = tid >> 6;
    const int c    = lane & 15;
    const int g    = lane >> 4;
    const int tok0 = blockIdx.x * 128;

    // per-lane packed-record slot offsets (uint4 units; 0 -> zero slot)
    const int o1 = (lane < 32) ? (1 + lane) : 0;
    const int o2 = ((lane & 8) == 0) ? (1 + ((lane >> 4) << 3) + (lane & 7)) : 0;
    const int cc0 = wv * 16;

    // ---- pipeline prologue: issue loads for chunks 0,1,2 into slots 0,1,2 ----
    FragU F0[4], F1[4], A2[4];
    #pragma unroll
    for (int p = 0; p < 3; ++p) {
        const int cc = cc0 + p;
        F0[p].q = (ws + cc * 66)[o1];
        F1[p].q = (ws + cc * 66 + 33)[o1];
        A2[p].q = (ws + 4224 + cc * 33)[o2];
    }

    // ---- prefix: threads 0-127, one thread per token ----
    float h[8];
    if (tid < 128) {
        const int t = tok0 + tid;
        const float4* xr = (const float4*)(x + (size_t)t * 8);
        float4 xa = xr[0], xb = xr[1];
        float xv[8] = {xa.x, xa.y, xa.z, xa.w, xb.x, xb.y, xb.z, xb.w};

        float qm[8];
        {
            float cp = 1.0f;
            #pragma unroll
            for (int f = 0; f < 8; ++f) {
                float acc = 0.0f;
                #pragma unroll
                for (int e = 0; e < 8; ++e) acc += xv[e] * Wq[f * 8 + e];
                cp *= __cosf(acc);
                qm[f] = cp;
            }
        }
        float mu = 0.0f;
        #pragma unroll
        for (int f = 0; f < 8; ++f) {
            float acc = 0.0f;
            #pragma unroll
            for (int e = 0; e < 8; ++e) acc += qm[e] * Wo[f * 8 + e];
            h[f] = xv[f] + acc;
            mu += h[f];
        }
        mu *= 0.125f;
        float var = 0.0f;
        #pragma unroll
        for (int i = 0; i < 8; ++i) { float d = h[i] - mu; var += d * d; }
        var *= 0.125f;
        float rs = rsqrtf(var + LN_EPS);
        #pragma unroll
        for (int i = 0; i < 8; ++i) h[i] = (h[i] - mu) * rs * g1[i] + beta1[i];

        float m[8];
        {
            float cp = 1.0f;
            #pragma unroll
            for (int i = 0; i < 8; ++i) { cp *= __cosf(h[i]); m[i] = cp; }
        }
        uint4 mq;
        mq.x = cvtpk(m[0], m[1]); mq.y = cvtpk(m[2], m[3]);
        mq.z = cvtpk(m[4], m[5]); mq.w = cvtpk(m[6], m[7]);
        mS[tid] = mq;
    }
    __syncthreads();

    // ---- B1 fragments: 8 token-tiles (k=8g+j; g0: m, g1 j0: bias row 1.0) ----
    FragU B1[8];
    #pragma unroll
    for (int T = 0; T < 8; ++T) {
        uint4 mr = mS[T * 16 + c];
        B1[T].u[0] = (g == 0) ? mr.x : ((g == 1) ? 0x00003F80u : 0u);
        B1[T].u[1] = (g == 0) ? mr.y : 0u;
        B1[T].u[2] = (g == 0) ? mr.z : 0u;
        B1[T].u[3] = (g == 0) ? mr.w : 0u;
    }

    // ---- pinned zero C-tuple ----
    f32x4 z4 = {0.f, 0.f, 0.f, 0.f};
    asm volatile("" : "+v"(z4));

    f32x4 acc[8] = {{0,0,0,0},{0,0,0,0},{0,0,0,0},{0,0,0,0},
                    {0,0,0,0},{0,0,0,0},{0,0,0,0},{0,0,0,0}};
    // guard: VALU writes (acc init / B1) -> asm MFMA reads at compiler boundary
    asm volatile("s_nop 3" ::: "memory");

    // ---- FFN: 16 chunks, 4-slot rotation / distance-3 prefetch, asm T-bodies ----
    #pragma unroll
    for (int i = 0; i < 16; ++i) {
        const int cur = i & 3;
        if (i + 3 < 16) {
            const int nslot = (i + 3) & 3;
            const int cc = cc0 + i + 3;
            F0[nslot].q = (ws + cc * 66)[o1];
            F1[nslot].q = (ws + cc * 66 + 33)[o1];
            A2[nslot].q = (ws + 4224 + cc * 33)[o2];
        }
        __builtin_amdgcn_s_setprio(1);
        TB_A(acc[0], F0[cur].v, F1[cur].v, A2[cur].v, B1[0].v);
        TB_B(acc[1], F0[cur].v, F1[cur].v, A2[cur].v, B1[1].v);
        TB_A(acc[2], F0[cur].v, F1[cur].v, A2[cur].v, B1[2].v);
        TB_B(acc[3], F0[cur].v, F1[cur].v, A2[cur].v, B1[3].v);
        TB_A(acc[4], F0[cur].v, F1[cur].v, A2[cur].v, B1[4].v);
        TB_B(acc[5], F0[cur].v, F1[cur].v, A2[cur].v, B1[5].v);
        TB_A(acc[6], F0[cur].v, F1[cur].v, A2[cur].v, B1[6].v);
        TB_B(acc[7], F0[cur].v, F1[cur].v, A2[cur].v, B1[7].v);
        __builtin_amdgcn_s_setprio(0);
    }
    // guard: asm MFMA writes acc -> compiler-generated LDS stores read acc
    asm volatile("s_nop 7\n\ts_nop 7" ::: "memory");

    // ---- write partial fragments: part[wv][tok][e] ----
    if (g < 2) {
        #pragma unroll
        for (int T = 0; T < 8; ++T) {
            *(f32x4*)&part[wv][T * 16 + c][4 * g] = acc[T];
        }
    }
    __syncthreads();

    // ---- threads 0-127: reduce partials + LN2 + store ----
    if (tid < 128) {
        float ffnv[8];
        #pragma unroll
        for (int e = 0; e < 8; ++e)
            ffnv[e] = part[0][tid][e] + part[1][tid][e]
                    + part[2][tid][e] + part[3][tid][e];

        float o[8];
        float mu2 = 0.0f;
        #pragma unroll
        for (int i = 0; i < 8; ++i) { o[i] = h[i] + ffnv[i] + b2[i]; mu2 += o[i]; }
        mu2 *= 0.125f;
        float v2 = 0.0f;
        #pragma unroll
        for (int i = 0; i < 8; ++i) { float d = o[i] - mu2; v2 += d * d; }
        v2 *= 0.125f;
        float rs2 = rsqrtf(v2 + LN_EPS);

        float res[8];
        #pragma unroll
        for (int i = 0; i < 8; ++i) res[i] = (o[i] - mu2) * rs2 * g2[i] + beta2[i];

        float4* orow = (float4*)(out + (size_t)(tok0 + tid) * 8);
        orow[0] = make_float4(res[0], res[1], res[2], res[3]);
        orow[1] = make_float4(res[4], res[5], res[6], res[7]);
    }
}

extern "C" void kernel_launch(void* const* d_in, const int* in_sizes, int n_in,
                              void* d_out, int out_size, void* d_ws, size_t ws_size,
                              hipStream_t stream) {
    const float* x     = (const float*)d_in[0];
    const float* Wq    = (const float*)d_in[1];
    const float* Wo    = (const float*)d_in[2];
    const float* W1    = (const float*)d_in[3];
    const float* b1    = (const float*)d_in[4];
    const float* W2    = (const float*)d_in[5];
    const float* b2    = (const float*)d_in[6];
    const float* g1    = (const float*)d_in[7];
    const float* beta1 = (const float*)d_in[8];
    const float* g2    = (const float*)d_in[9];
    const float* beta2 = (const float*)d_in[10];
    float* out = (float*)d_out;
    uint4* ws = (uint4*)d_ws;   // 6336*16 = 101.4 KB

    tbq_prep<<<25, 256, 0, stream>>>(W1, b1, W2, ws);

    const int ntok = in_sizes[0] / 8;      // 131072
    const int grid = ntok / 128;           // 1024 blocks, 4 waves f-split
    tbq_mfma<<<grid, 256, 0, stream>>>(x, Wq, Wo, b2, g1, beta1, g2, beta2, ws, out);
}